// Round 1
// baseline (1040.364 us; speedup 1.0000x reference)
//
#include <hip/hip_runtime.h>
#include <stdint.h>

// Problem constants
#define BATCH 4096
#define DIM   2048          // IN_DIM == HID == OUT == 2048
#define ROWS2 8192          // 2*BATCH (x1 and x2 stacked)
#define LROW  8191          // logits row length = 2B-1

typedef __attribute__((ext_vector_type(8))) short bf16x8;
typedef __attribute__((ext_vector_type(4))) short s16x4;
typedef __attribute__((ext_vector_type(4))) float f32x4;

typedef __attribute__((address_space(1))) void gvoid;
typedef __attribute__((address_space(3))) void lvoid;
#define GLOAD16(g, l) __builtin_amdgcn_global_load_lds((gvoid*)(g), (lvoid*)(l), 16, 0, 0)

// float -> bf16 round-to-nearest-even (finite inputs)
__device__ __forceinline__ unsigned short f2bf(float f) {
    unsigned int u = __float_as_uint(f);
    unsigned int r = (u + 0x7FFFu + ((u >> 16) & 1u)) >> 16;
    return (unsigned short)r;
}

// ---------------- conversion kernels ----------------

// 8 floats/thread -> 8 bf16 (16B store). n must be divisible by 8*256.
__global__ __launch_bounds__(256) void k_cvt8(const float* __restrict__ src,
                                              unsigned short* __restrict__ dst) {
    size_t i = ((size_t)blockIdx.x * 256 + threadIdx.x) * 8;
    float4 v0 = *(const float4*)(src + i);
    float4 v1 = *(const float4*)(src + i + 4);
    bf16x8 p;
    p[0] = (short)f2bf(v0.x); p[1] = (short)f2bf(v0.y);
    p[2] = (short)f2bf(v0.z); p[3] = (short)f2bf(v0.w);
    p[4] = (short)f2bf(v1.x); p[5] = (short)f2bf(v1.y);
    p[6] = (short)f2bf(v1.z); p[7] = (short)f2bf(v1.w);
    *(bf16x8*)(dst + i) = p;
}

// W [k][n] f32 -> WT [n][k] bf16, 32x32 LDS tile transpose
__global__ __launch_bounds__(256) void k_transpose_cvt(const float* __restrict__ W,
                                                       unsigned short* __restrict__ WT) {
    __shared__ unsigned short t[32][33];
    int n0 = blockIdx.x * 32, k0 = blockIdx.y * 32;
    int tx = threadIdx.x, ty = threadIdx.y;  // (32,8)
#pragma unroll
    for (int i = 0; i < 4; i++) {
        int k = ty + i * 8;
        t[k][tx] = f2bf(W[(size_t)(k0 + k) * DIM + n0 + tx]);
    }
    __syncthreads();
#pragma unroll
    for (int i = 0; i < 4; i++) {
        int r = ty + i * 8;
        WT[(size_t)(n0 + r) * DIM + k0 + tx] = t[tx][r];
    }
}

// ---------------- main GEMM (A [M,K] bf16) x (B [N,K] bf16)^T ----------------
// EPI 0: C[m][n] = acc + bias[n]   (f32, ldc = DIM)
// EPI 1: gram same-side (QQ): skip diag, logits[i][1 + j - (j>i)] = acc/T
// EPI 2: gram cross (QK): diag -> col 0, else logits[i][4096 + j - (j>i)] = acc/T
template <int EPI>
__global__ __launch_bounds__(256) void k_gemm_bt(const short* __restrict__ A,
                                                 const short* __restrict__ Bm,
                                                 float* __restrict__ C,
                                                 const float* __restrict__ bias,
                                                 const float* __restrict__ Tptr,
                                                 int K, int ldc) {
    __shared__ __align__(16) short As[128 * 32];
    __shared__ __align__(16) short Bs[128 * 32];

    const int tid = threadIdx.x;
    const int w = tid >> 6, l = tid & 63;
    const int m0 = blockIdx.y * 128, n0 = blockIdx.x * 128;
    const int wRow = (w >> 1) * 64, wCol = (w & 1) * 64;
    const int lr = l & 15, quad = l >> 4;

    // staging: chunk c covers As rows [c*16, c*16+16); lane l -> row c*16 + l/4, k-off (l&3)*8
    const int c0 = w * 2, c1 = w * 2 + 1;
    const int lrow = l >> 2, lkoff = (l & 3) * 8;
    const short* gA0 = A + (size_t)(m0 + c0 * 16 + lrow) * K + lkoff;
    const short* gA1 = A + (size_t)(m0 + c1 * 16 + lrow) * K + lkoff;
    const short* gB0 = Bm + (size_t)(n0 + c0 * 16 + lrow) * K + lkoff;
    const short* gB1 = Bm + (size_t)(n0 + c1 * 16 + lrow) * K + lkoff;
    short* lA0 = As + c0 * 512; short* lA1 = As + c1 * 512;
    short* lB0 = Bs + c0 * 512; short* lB1 = Bs + c1 * 512;

    const int aoff = (wRow + lr) * 32 + quad * 8;
    const int boff = (wCol + lr) * 32 + quad * 8;

    f32x4 acc[4][4] = {};

    for (int k0 = 0; k0 < K; k0 += 32) {
        GLOAD16(gA0, lA0); GLOAD16(gA1, lA1);
        GLOAD16(gB0, lB0); GLOAD16(gB1, lB1);
        gA0 += 32; gA1 += 32; gB0 += 32; gB1 += 32;
        __syncthreads();

        bf16x8 af[4], bfr[4];
#pragma unroll
        for (int i = 0; i < 4; i++) {
            af[i]  = *(const bf16x8*)(As + aoff + i * 512);
            bfr[i] = *(const bf16x8*)(Bs + boff + i * 512);
        }
#pragma unroll
        for (int mi = 0; mi < 4; mi++)
#pragma unroll
            for (int ni = 0; ni < 4; ni++)
                acc[mi][ni] = __builtin_amdgcn_mfma_f32_16x16x32_bf16(af[mi], bfr[ni],
                                                                      acc[mi][ni], 0, 0, 0);
        __syncthreads();
    }

    if (EPI == 0) {
#pragma unroll
        for (int mi = 0; mi < 4; mi++) {
            int row = m0 + wRow + mi * 16 + quad * 4;
#pragma unroll
            for (int ni = 0; ni < 4; ni++) {
                int col = n0 + wCol + ni * 16 + lr;
                float bv = bias[col];
#pragma unroll
                for (int r = 0; r < 4; r++)
                    C[(size_t)(row + r) * ldc + col] = acc[mi][ni][r] + bv;
            }
        }
    } else {
        float invT = 1.0f / Tptr[0];
#pragma unroll
        for (int mi = 0; mi < 4; mi++) {
            int ibase = m0 + wRow + mi * 16 + quad * 4;
#pragma unroll
            for (int ni = 0; ni < 4; ni++) {
                int j = n0 + wCol + ni * 16 + lr;
#pragma unroll
                for (int r = 0; r < 4; r++) {
                    int i = ibase + r;
                    float v = acc[mi][ni][r] * invT;
                    int dc;
                    if (EPI == 1) {
                        if (j == i) continue;
                        dc = 1 + j - (j > i);
                    } else {
                        dc = (j == i) ? 0 : (4096 + j - (j > i));
                    }
                    C[(size_t)i * LROW + dc] = v;
                }
            }
        }
    }
}

// ---------------- batchnorm stats / apply ----------------

// partial column sums over 256-row chunks; grid (8, 32), block 256
__global__ __launch_bounds__(256) void k_bn_stats(const float* __restrict__ h,
                                                  float* __restrict__ musum,
                                                  float* __restrict__ sqsum) {
    int col = blockIdx.x * 256 + threadIdx.x;
    int r0 = blockIdx.y * 256;
    int half = r0 >> 12;
    float s = 0.f, s2 = 0.f;
#pragma unroll 8
    for (int r = r0; r < r0 + 256; r++) {
        float v = h[(size_t)r * DIM + col];
        s += v; s2 += v * v;
    }
    atomicAdd(&musum[half * DIM + col], s);
    atomicAdd(&sqsum[half * DIM + col], s2);
}

// BN (training stats, biased var) + ReLU -> bf16
__global__ __launch_bounds__(256) void k_bn_apply(const float* __restrict__ h,
                                                  const float* __restrict__ musum,
                                                  const float* __restrict__ sqsum,
                                                  const float* __restrict__ gamma,
                                                  const float* __restrict__ beta,
                                                  unsigned short* __restrict__ out) {
    size_t idx = ((size_t)blockIdx.x * 256 + threadIdx.x) * 4;
    int col = (int)(idx & (DIM - 1));
    int half = (int)(idx >> 23);  // rows >= 4096 <=> idx >= 2^23
    float4 v = *(const float4*)(h + idx);
    float vv[4] = {v.x, v.y, v.z, v.w};
    const float inv_n = 1.0f / 4096.0f;
    s16x4 o;
#pragma unroll
    for (int t = 0; t < 4; t++) {
        int c = col + t;
        float mu = musum[half * DIM + c] * inv_n;
        float var = sqsum[half * DIM + c] * inv_n - mu * mu;
        float sc = rsqrtf(var + 1e-5f) * gamma[c];
        float x = (vv[t] - mu) * sc + beta[c];
        x = fmaxf(x, 0.0f);
        o[t] = (short)f2bf(x);
    }
    *(s16x4*)(out + idx) = o;
}

// ---------------- row l2 norm ----------------

__global__ __launch_bounds__(256) void k_rownorm(const float* __restrict__ g,
                                                 float* __restrict__ inv) {
    int row = blockIdx.x;
    const float* p = g + (size_t)row * DIM;
    float s = 0.f;
#pragma unroll
    for (int c = threadIdx.x * 4; c < DIM; c += 1024) {
        float4 v = *(const float4*)(p + c);
        s += v.x * v.x + v.y * v.y + v.z * v.z + v.w * v.w;
    }
#pragma unroll
    for (int off = 32; off; off >>= 1) s += __shfl_down(s, off);
    __shared__ float wsum[4];
    if ((threadIdx.x & 63) == 0) wsum[threadIdx.x >> 6] = s;
    __syncthreads();
    if (threadIdx.x == 0) inv[row] = rsqrtf(wsum[0] + wsum[1] + wsum[2] + wsum[3]);
}

__global__ __launch_bounds__(256) void k_qnorm(const float* __restrict__ g,
                                               const float* __restrict__ inv,
                                               unsigned short* __restrict__ q) {
    size_t idx = ((size_t)blockIdx.x * 256 + threadIdx.x) * 4;
    int row = (int)(idx >> 11);
    float iv = inv[row];
    float4 v = *(const float4*)(g + idx);
    float vv[4] = {v.x, v.y, v.z, v.w};
    s16x4 o;
#pragma unroll
    for (int t = 0; t < 4; t++) o[t] = (short)f2bf(vv[t] * iv);
    *(s16x4*)(q + idx) = o;
}

// ---------------- launch ----------------

extern "C" void kernel_launch(void* const* d_in, const int* in_sizes, int n_in,
                              void* d_out, int out_size, void* d_ws, size_t ws_size,
                              hipStream_t stream) {
    const float* x1    = (const float*)d_in[0];
    const float* x2    = (const float*)d_in[1];
    const float* W1    = (const float*)d_in[2];
    const float* b1    = (const float*)d_in[3];
    const float* gamma = (const float*)d_in[4];
    const float* beta  = (const float*)d_in[5];
    const float* W2    = (const float*)d_in[6];
    const float* b2    = (const float*)d_in[7];
    const float* Tp    = (const float*)d_in[9];
    float* out = (float*)d_out;

    char* ws = (char*)d_ws;
    // R1: 32MB bf16 [8192,2048] — X, then Hn, then Q
    unsigned short* R1 = (unsigned short*)ws;
    // R2: 64MB f32 [8192,2048] — h, then g
    float* R2 = (float*)(ws + ((size_t)32 << 20));
    unsigned short* W1T = (unsigned short*)(ws + ((size_t)96 << 20));
    unsigned short* W2T = (unsigned short*)(ws + ((size_t)104 << 20));
    float* musum = (float*)(ws + ((size_t)112 << 20));   // [2][2048]
    float* sqsum = musum + 2 * DIM;                      // [2][2048]
    float* rowinv = sqsum + 2 * DIM;                     // [8192]

    // zero stat accumulators (ws is poisoned each call)
    hipMemsetAsync(musum, 0, 4 * DIM * sizeof(float), stream);

    // 1. convert inputs
    k_cvt8<<<4096, 256, 0, stream>>>(x1, R1);
    k_cvt8<<<4096, 256, 0, stream>>>(x2, R1 + (size_t)BATCH * DIM);
    k_transpose_cvt<<<dim3(64, 64), dim3(32, 8), 0, stream>>>(W1, W1T);
    k_transpose_cvt<<<dim3(64, 64), dim3(32, 8), 0, stream>>>(W2, W2T);

    // 2. h = X @ W1 + b1   (M=8192, N=2048)
    k_gemm_bt<0><<<dim3(16, 64), 256, 0, stream>>>((const short*)R1, (const short*)W1T,
                                                   R2, b1, nullptr, DIM, DIM);
    // 3. BN stats + apply + ReLU -> Hn (bf16, overwrites X)
    k_bn_stats<<<dim3(8, 32), 256, 0, stream>>>(R2, musum, sqsum);
    k_bn_apply<<<16384, 256, 0, stream>>>(R2, musum, sqsum, gamma, beta, R1);

    // 4. g = Hn @ W2 + b2
    k_gemm_bt<0><<<dim3(16, 64), 256, 0, stream>>>((const short*)R1, (const short*)W2T,
                                                   R2, b2, nullptr, DIM, DIM);
    // 5. row l2 normalize -> Q (bf16, overwrites Hn)
    k_rownorm<<<8192, 256, 0, stream>>>(R2, rowinv);
    k_qnorm<<<16384, 256, 0, stream>>>(R2, rowinv, R1);

    // 6. gram products scattered into logits
    const short* q1 = (const short*)R1;
    const short* q2 = (const short*)(R1 + (size_t)BATCH * DIM);
    float* L1 = out;
    float* L2 = out + (size_t)BATCH * LROW;
    k_gemm_bt<1><<<dim3(32, 32), 256, 0, stream>>>(q1, q1, L1, nullptr, Tp, DIM, LROW);
    k_gemm_bt<2><<<dim3(32, 32), 256, 0, stream>>>(q1, q2, L1, nullptr, Tp, DIM, LROW);
    k_gemm_bt<1><<<dim3(32, 32), 256, 0, stream>>>(q2, q2, L2, nullptr, Tp, DIM, LROW);
    k_gemm_bt<2><<<dim3(32, 32), 256, 0, stream>>>(q2, q1, L2, nullptr, Tp, DIM, LROW);

    // 7. labels = zeros (int32 0 == f32 0 bitwise)
    hipMemsetAsync(out + (size_t)2 * BATCH * LROW, 0, BATCH * sizeof(int), stream);
}

// Round 2
// 835.102 us; speedup vs baseline: 1.2458x; 1.2458x over previous
//
#include <hip/hip_runtime.h>
#include <stdint.h>

#define BATCH 4096
#define DIM   2048
#define LROW  8191

typedef __attribute__((ext_vector_type(8))) short bf16x8;
typedef __attribute__((ext_vector_type(4))) float f32x4;

typedef __attribute__((address_space(1))) void gvoid;
typedef __attribute__((address_space(3))) void lvoid;
#define GLOAD16(g, l) __builtin_amdgcn_global_load_lds((gvoid*)(g), (lvoid*)(l), 16, 0, 0)

// float -> bf16 round-to-nearest-even
__device__ __forceinline__ unsigned short f2bf(float f) {
    unsigned int u = __float_as_uint(f);
    return (unsigned short)((u + 0x7FFFu + ((u >> 16) & 1u)) >> 16);
}
__device__ __forceinline__ float bf2f(unsigned short s) {
    return __uint_as_float(((unsigned int)s) << 16);
}

// ---------------- conversion kernels ----------------

__global__ __launch_bounds__(256) void k_cvt8(const float* __restrict__ src,
                                              unsigned short* __restrict__ dst) {
    size_t i = ((size_t)blockIdx.x * 256 + threadIdx.x) * 8;
    float4 v0 = *(const float4*)(src + i);
    float4 v1 = *(const float4*)(src + i + 4);
    bf16x8 p;
    p[0] = (short)f2bf(v0.x); p[1] = (short)f2bf(v0.y);
    p[2] = (short)f2bf(v0.z); p[3] = (short)f2bf(v0.w);
    p[4] = (short)f2bf(v1.x); p[5] = (short)f2bf(v1.y);
    p[6] = (short)f2bf(v1.z); p[7] = (short)f2bf(v1.w);
    *(bf16x8*)(dst + i) = p;
}

// W [k][n] f32 -> WT [n][k] bf16
__global__ __launch_bounds__(256) void k_transpose_cvt(const float* __restrict__ W,
                                                       unsigned short* __restrict__ WT) {
    __shared__ unsigned short t[32][33];
    int n0 = blockIdx.x * 32, k0 = blockIdx.y * 32;
    int tx = threadIdx.x, ty = threadIdx.y;  // (32,8)
#pragma unroll
    for (int i = 0; i < 4; i++) {
        int k = ty + i * 8;
        t[k][tx] = f2bf(W[(size_t)(k0 + k) * DIM + n0 + tx]);
    }
    __syncthreads();
#pragma unroll
    for (int i = 0; i < 4; i++) {
        int r = ty + i * 8;
        WT[(size_t)(n0 + r) * DIM + k0 + tx] = t[tx][r];
    }
}

// ---------------- unified GEMM: (A [M,K] bf16) x (B [N,K] bf16)^T ----------------
// EPI 0: predictor GEMM1 — out0 = bf16(acc+bias), column sum/sumsq atomics into st0/st1
// EPI 1: predictor GEMM2 — out0 = bf16(acc+bias), row sum-of-squares atomics into st0
// EPI 2: sym gram (upper-tri grid, blockIdx.y selects q1/L1 vs q2/L2), mirror via LDS transpose
// EPI 3: cross gram q1@q2^T — writes L1 normally, L2 transposed
template <int EPI>
__global__ __launch_bounds__(256) void k_gemm(const short* __restrict__ A_,
                                              const short* __restrict__ B_,
                                              void* __restrict__ out0,
                                              void* __restrict__ out1,
                                              const float* __restrict__ bias,
                                              float* __restrict__ st0,
                                              float* __restrict__ st1,
                                              const float* __restrict__ Tptr,
                                              int K) {
    __shared__ __align__(16) short smem[2 * 128 * 32];
    short* As = smem;
    short* Bs = smem + 128 * 32;

    const int tid = threadIdx.x;
    const int w = tid >> 6, l = tid & 63;
    const int wRow = (w >> 1) * 64, wCol = (w & 1) * 64;
    const int lr = l & 15, quad = l >> 4;

    int m0, n0, bi = 0, bj = 0;
    const short* A;
    const short* Bm;
    if (EPI == 2) {
        int t = blockIdx.x;
        while (t >= 32 - bi) { t -= 32 - bi; bi++; }
        bj = bi + t;
        m0 = bi * 128; n0 = bj * 128;
        const short* Q = A_ + (size_t)blockIdx.y * BATCH * DIM;
        A = Q; Bm = Q;
    } else {
        m0 = blockIdx.y * 128; n0 = blockIdx.x * 128;
        A = A_; Bm = B_;
    }

    // staging: chunk c covers rows [c*16, c*16+16); lane l -> row c*16+l/4, k-off (l&3)*8
    const int c0 = w * 2, c1 = w * 2 + 1;
    const int lrow = l >> 2, lkoff = (l & 3) * 8;
    const short* gA0 = A + (size_t)(m0 + c0 * 16 + lrow) * K + lkoff;
    const short* gA1 = A + (size_t)(m0 + c1 * 16 + lrow) * K + lkoff;
    const short* gB0 = Bm + (size_t)(n0 + c0 * 16 + lrow) * K + lkoff;
    const short* gB1 = Bm + (size_t)(n0 + c1 * 16 + lrow) * K + lkoff;
    short* lA0 = As + c0 * 512; short* lA1 = As + c1 * 512;
    short* lB0 = Bs + c0 * 512; short* lB1 = Bs + c1 * 512;

    const int aoff = (wRow + lr) * 32 + quad * 8;
    const int boff = (wCol + lr) * 32 + quad * 8;

    f32x4 acc[4][4] = {};

    for (int k0 = 0; k0 < K; k0 += 32) {
        GLOAD16(gA0, lA0); GLOAD16(gA1, lA1);
        GLOAD16(gB0, lB0); GLOAD16(gB1, lB1);
        gA0 += 32; gA1 += 32; gB0 += 32; gB1 += 32;
        __syncthreads();

        bf16x8 af[4], bfr[4];
#pragma unroll
        for (int i = 0; i < 4; i++) {
            af[i]  = *(const bf16x8*)(As + aoff + i * 512);
            bfr[i] = *(const bf16x8*)(Bs + boff + i * 512);
        }
#pragma unroll
        for (int mi = 0; mi < 4; mi++)
#pragma unroll
            for (int ni = 0; ni < 4; ni++)
                acc[mi][ni] = __builtin_amdgcn_mfma_f32_16x16x32_bf16(af[mi], bfr[ni],
                                                                      acc[mi][ni], 0, 0, 0);
        __syncthreads();
    }

    if (EPI == 0) {
        unsigned short* H = (unsigned short*)out0;
        const int half = m0 >> 12;  // m0 >= 4096 -> second batch
        float s[4] = {0.f, 0.f, 0.f, 0.f}, s2[4] = {0.f, 0.f, 0.f, 0.f};
#pragma unroll
        for (int ni = 0; ni < 4; ni++) {
            int col = n0 + wCol + ni * 16 + lr;
            float bv = bias[col];
#pragma unroll
            for (int mi = 0; mi < 4; mi++) {
                int row = m0 + wRow + mi * 16 + quad * 4;
#pragma unroll
                for (int r = 0; r < 4; r++) {
                    float v = acc[mi][ni][r] + bv;
                    H[(size_t)(row + r) * DIM + col] = f2bf(v);
                    s[ni] += v; s2[ni] += v * v;
                }
            }
        }
#pragma unroll
        for (int ni = 0; ni < 4; ni++) {
            float a = s[ni], b = s2[ni];
            a += __shfl_xor(a, 16); b += __shfl_xor(b, 16);
            a += __shfl_xor(a, 32); b += __shfl_xor(b, 32);
            if (quad == 0) {
                int col = n0 + wCol + ni * 16 + lr;
                atomicAdd(&st0[half * DIM + col], a);
                atomicAdd(&st1[half * DIM + col], b);
            }
        }
    } else if (EPI == 1) {
        unsigned short* G = (unsigned short*)out0;
        float bv[4];
#pragma unroll
        for (int ni = 0; ni < 4; ni++) bv[ni] = bias[n0 + wCol + ni * 16 + lr];
#pragma unroll
        for (int mi = 0; mi < 4; mi++) {
            int rowb = m0 + wRow + mi * 16 + quad * 4;
#pragma unroll
            for (int r = 0; r < 4; r++) {
                int row = rowb + r;
                float p = 0.f;
#pragma unroll
                for (int ni = 0; ni < 4; ni++) {
                    int col = n0 + wCol + ni * 16 + lr;
                    float v = acc[mi][ni][r] + bv[ni];
                    G[(size_t)row * DIM + col] = f2bf(v);
                    p += v * v;
                }
                p += __shfl_xor(p, 1); p += __shfl_xor(p, 2);
                p += __shfl_xor(p, 4); p += __shfl_xor(p, 8);
                if (lr == 0) atomicAdd(&st0[row], p);
            }
        }
    } else {
        const float invT = 1.0f / Tptr[0];
        float* L  = (EPI == 2) ? (float*)(blockIdx.y ? out1 : out0) : (float*)out0;
        float* Lm = (EPI == 2) ? L : (float*)out1;
        const bool diagblk = (EPI == 2) && (bi == bj);
        // normal writes: rows i (m-block), cols from j (n-block)
#pragma unroll
        for (int mi = 0; mi < 4; mi++) {
            int ibase = m0 + wRow + mi * 16 + quad * 4;
#pragma unroll
            for (int ni = 0; ni < 4; ni++) {
                int j = n0 + wCol + ni * 16 + lr;
#pragma unroll
                for (int r = 0; r < 4; r++) {
                    int i = ibase + r;
                    float v = acc[mi][ni][r] * invT;
                    int dc;
                    if (EPI == 2) {
                        if (diagblk) {
                            if (j == i) continue;
                            dc = 1 + j - (j > i);
                        } else {
                            dc = j;  // bi<bj => j>i => 1+j-1 == j
                        }
                    } else {
                        dc = (j == i) ? 0 : (4096 + j - (j > i));
                    }
                    L[(size_t)i * LROW + dc] = v;
                }
            }
        }
        // mirror writes via per-wave 16x16 LDS transpose (exact same fp values)
        if (EPI == 3 || bi != bj) {
            float* tsc = (float*)smem + w * 320;  // 16 rows x pitch 20
#pragma unroll
            for (int mi = 0; mi < 4; mi++) {
                int I0 = m0 + wRow + mi * 16;
#pragma unroll
                for (int ni = 0; ni < 4; ni++) {
                    int J0 = n0 + wCol + ni * 16;
#pragma unroll
                    for (int r = 0; r < 4; r++)
                        tsc[(quad * 4 + r) * 20 + lr] = acc[mi][ni][r];
                    int a = I0 + lr;  // original row index -> mirror col source
#pragma unroll
                    for (int r = 0; r < 4; r++) {
                        int b = J0 + quad * 4 + r;  // original col index -> mirror row
                        float tv = tsc[lr * 20 + quad * 4 + r] * invT;
                        int dcm;
                        if (EPI == 2) dcm = 1 + a;  // a < b guaranteed (bi<bj)
                        else dcm = (a == b) ? 0 : (4096 + a - (a > b));
                        Lm[(size_t)b * LROW + dcm] = tv;
                    }
                }
            }
        }
    }
}

// ---------------- small elementwise kernels ----------------

// scale/shift from accumulated sums (in-place: musum->scale, sqsum->shift)
__global__ __launch_bounds__(256) void k_bn_coef(float* __restrict__ musum,
                                                 float* __restrict__ sqsum,
                                                 const float* __restrict__ gamma,
                                                 const float* __restrict__ beta) {
    int i = blockIdx.x * 256 + threadIdx.x;  // 0..4095 = half*DIM+col
    int col = i & (DIM - 1);
    const float inv_n = 1.0f / 4096.0f;
    float mu = musum[i] * inv_n;
    float var = sqsum[i] * inv_n - mu * mu;
    float sc = rsqrtf(var + 1e-5f) * gamma[col];
    musum[i] = sc;
    sqsum[i] = beta[col] - mu * sc;
}

// Hn = relu(h*scale+shift), bf16 in-place
__global__ __launch_bounds__(256) void k_bn_apply(unsigned short* __restrict__ H,
                                                  const float* __restrict__ scale,
                                                  const float* __restrict__ shift) {
    size_t idx = ((size_t)blockIdx.x * 256 + threadIdx.x) * 8;
    int col = (int)(idx & (DIM - 1));
    int base = ((int)(idx >> 23)) * DIM + col;  // half*DIM + col
    bf16x8 hv = *(bf16x8*)(H + idx);
    bf16x8 o;
#pragma unroll
    for (int t = 0; t < 8; t++) {
        float x = bf2f((unsigned short)hv[t]);
        x = fmaxf(x * scale[base + t] + shift[base + t], 0.f);
        o[t] = (short)f2bf(x);
    }
    *(bf16x8*)(H + idx) = o;
}

__global__ __launch_bounds__(256) void k_rowinv(float* __restrict__ rss) {
    int i = blockIdx.x * 256 + threadIdx.x;  // 8192 rows
    rss[i] = rsqrtf(rss[i]);
}

__global__ __launch_bounds__(256) void k_qnorm(const unsigned short* __restrict__ G,
                                               const float* __restrict__ inv,
                                               unsigned short* __restrict__ Q) {
    size_t idx = ((size_t)blockIdx.x * 256 + threadIdx.x) * 8;
    float iv = inv[idx >> 11];
    bf16x8 g = *(const bf16x8*)(G + idx);
    bf16x8 o;
#pragma unroll
    for (int t = 0; t < 8; t++) o[t] = (short)f2bf(bf2f((unsigned short)g[t]) * iv);
    *(bf16x8*)(Q + idx) = o;
}

// ---------------- launch ----------------

extern "C" void kernel_launch(void* const* d_in, const int* in_sizes, int n_in,
                              void* d_out, int out_size, void* d_ws, size_t ws_size,
                              hipStream_t stream) {
    const float* x1    = (const float*)d_in[0];
    const float* x2    = (const float*)d_in[1];
    const float* W1    = (const float*)d_in[2];
    const float* b1    = (const float*)d_in[3];
    const float* gamma = (const float*)d_in[4];
    const float* beta  = (const float*)d_in[5];
    const float* W2    = (const float*)d_in[6];
    const float* b2    = (const float*)d_in[7];
    const float* Tp    = (const float*)d_in[9];
    float* out = (float*)d_out;

    char* ws = (char*)d_ws;
    unsigned short* R1  = (unsigned short*)ws;                       // 32MB: Xb, then g
    unsigned short* R3  = (unsigned short*)(ws + (32ull << 20));     // 32MB: H/Hn, then Q
    unsigned short* W1T = (unsigned short*)(ws + (64ull << 20));     // 8MB
    unsigned short* W2T = (unsigned short*)(ws + (72ull << 20));     // 8MB
    float* musum = (float*)(ws + (80ull << 20));                     // [2][2048]
    float* sqsum = musum + 2 * DIM;                                  // [2][2048]
    float* rss   = sqsum + 2 * DIM;                                  // [8192]

    // zero the stat accumulators (ws is poisoned each call)
    hipMemsetAsync(musum, 0, (4 * DIM + 8192) * sizeof(float), stream);

    // 1. convert inputs
    k_cvt8<<<4096, 256, 0, stream>>>(x1, R1);
    k_cvt8<<<4096, 256, 0, stream>>>(x2, R1 + (size_t)BATCH * DIM);
    k_transpose_cvt<<<dim3(64, 64), dim3(32, 8), 0, stream>>>(W1, W1T);
    k_transpose_cvt<<<dim3(64, 64), dim3(32, 8), 0, stream>>>(W2, W2T);

    // 2. h = X @ W1 + b1 (bf16 out + fused column stats)
    k_gemm<0><<<dim3(16, 64), 256, 0, stream>>>((const short*)R1, (const short*)W1T,
                                                R3, nullptr, b1, musum, sqsum, nullptr, DIM);
    // 3. BN coef + apply + ReLU (in-place on H)
    k_bn_coef<<<16, 256, 0, stream>>>(musum, sqsum, gamma, beta);
    k_bn_apply<<<8192, 256, 0, stream>>>(R3, musum, sqsum);

    // 4. g = Hn @ W2 + b2 (bf16 out + fused row sum-of-squares)
    k_gemm<1><<<dim3(16, 64), 256, 0, stream>>>((const short*)R3, (const short*)W2T,
                                                R1, nullptr, b2, rss, nullptr, nullptr, DIM);
    // 5. normalize rows -> Q bf16
    k_rowinv<<<32, 256, 0, stream>>>(rss);
    k_qnorm<<<8192, 256, 0, stream>>>(R1, rss, R3);

    // 6. gram products scattered into logits (symmetry-halved)
    const short* Q  = (const short*)R3;
    const short* Q2 = (const short*)(R3 + (size_t)BATCH * DIM);
    float* L1 = out;
    float* L2 = out + (size_t)BATCH * LROW;
    k_gemm<2><<<dim3(528, 2), 256, 0, stream>>>(Q, nullptr, L1, L2,
                                                nullptr, nullptr, nullptr, Tp, DIM);
    k_gemm<3><<<dim3(32, 32), 256, 0, stream>>>(Q, Q2, L1, L2,
                                                nullptr, nullptr, nullptr, Tp, DIM);

    // 7. labels = zeros
    hipMemsetAsync(out + (size_t)2 * BATCH * LROW, 0, BATCH * sizeof(int), stream);
}